// Round 1
// baseline (197.833 us; speedup 1.0000x reference)
//
#include <hip/hip_runtime.h>

// SSIM loss, fused separable Gaussian (11x11, sigma=1.5) over [32,3,512,512] f32.
// Strategy: per block, tile = 8 out rows x 256 out cols.
//  Phase 1 (vertical FIR): thread t owns padded column t (266 cols), streams 18
//   raw rows from GLOBAL directly into registers, accumulates 5 stats x 8 rows
//   (fully unrolled FIR, all register indices compile-time), writes to LDS.
//  Phase 2 (horizontal): thread handles 4 consecutive outputs; reads each stat
//   as 4 aligned float4 from LDS, 11-tap FMA per output, SSIM epilogue,
//   block reduce -> atomicAdd(d_out).
// zero kernel + finalize kernel (1 - sum/N) bracket the main kernel.

#define IH 512
#define IW 512
#define NBC 96              // 32 * 3
#define TH 8                // output rows per tile
#define TW 256              // output cols per tile
#define PW (TW + 10)        // 266 padded cols
#define RRN (TH + 10)       // 18 raw rows
#define LST 272             // LDS row stride (floats), 16B aligned
#define WTILES (IW / TW)    // 2
#define HTILES (IH / TH)    // 64
#define NPIX 25165824.0f    // 96*512*512

constexpr float GW[11] = {
    0.00102838f, 0.00759877f, 0.03600078f, 0.10936070f, 0.21300554f,
    0.26601173f,
    0.21300554f, 0.10936070f, 0.03600078f, 0.00759877f, 0.00102838f
};
constexpr float C1f = 0.0001f;  // 0.01^2
constexpr float C2f = 0.0009f;  // 0.03^2

__global__ void ssim_zero(float* out) { out[0] = 0.0f; }

__global__ void ssim_fin(float* out) {
    out[0] = 1.0f - out[0] * (1.0f / NPIX);
}

__global__ __launch_bounds__(256) void ssim_main(
    const float* __restrict__ pred,
    const float* __restrict__ targ,
    float* __restrict__ out)
{
    __shared__ __align__(16) float vlds[5][TH][LST];
    __shared__ float wsum[4];

    const int tid = threadIdx.x;
    const int bid = blockIdx.x;
    const int wt = bid % WTILES;
    const int ht = (bid / WTILES) % HTILES;
    const int bc = bid / (WTILES * HTILES);
    const int h0 = ht * TH;
    const int w0 = wt * TW;
    const float* __restrict__ P = pred + (size_t)bc * (IH * IW);
    const float* __restrict__ T = targ + (size_t)bc * (IH * IW);

    // ---------------- Phase 1: vertical FIR, global -> registers -> LDS ---
    for (int cc = tid; cc < PW; cc += 256) {
        const int w = w0 - 5 + cc;
        const bool wok = ((unsigned)w < (unsigned)IW);
        float a0[TH], a1[TH], a2[TH], a3[TH], a4[TH];
        #pragma unroll
        for (int r = 0; r < TH; ++r) { a0[r]=0.f; a1[r]=0.f; a2[r]=0.f; a3[r]=0.f; a4[r]=0.f; }

        #pragma unroll
        for (int rr = 0; rr < RRN; ++rr) {
            const int h = h0 - 5 + rr;
            float p = 0.0f, t = 0.0f;
            if (wok && ((unsigned)h < (unsigned)IH)) {
                p = P[h * IW + w];
                t = T[h * IW + w];
            }
            const float pp = p * p;
            const float tt = t * t;
            const float pt = p * t;
            #pragma unroll
            for (int ro = 0; ro < TH; ++ro) {
                const int k = rr - ro;          // compile-time after unroll
                if (k >= 0 && k < 11) {
                    const float g = GW[k];
                    a0[ro] = fmaf(g, p,  a0[ro]);
                    a1[ro] = fmaf(g, t,  a1[ro]);
                    a2[ro] = fmaf(g, pp, a2[ro]);
                    a3[ro] = fmaf(g, tt, a3[ro]);
                    a4[ro] = fmaf(g, pt, a4[ro]);
                }
            }
        }
        #pragma unroll
        for (int r = 0; r < TH; ++r) {
            vlds[0][r][cc] = a0[r];
            vlds[1][r][cc] = a1[r];
            vlds[2][r][cc] = a2[r];
            vlds[3][r][cc] = a3[r];
            vlds[4][r][cc] = a4[r];
        }
    }
    __syncthreads();

    // ---------------- Phase 2: horizontal conv + SSIM epilogue ------------
    float lsum = 0.0f;
    #pragma unroll
    for (int it = 0; it < 2; ++it) {
        const int chunk = tid + 256 * it;   // 0..511
        const int r  = chunk >> 6;          // 0..7
        const int c0 = (chunk & 63) << 2;   // 0..252, multiple of 4

        float o[5][4];
        #pragma unroll
        for (int s = 0; s < 5; ++s) {
            float x[16];
            const float4* base = reinterpret_cast<const float4*>(&vlds[s][r][c0]);
            const float4 v0 = base[0];
            const float4 v1 = base[1];
            const float4 v2 = base[2];
            const float4 v3 = base[3];
            x[0]=v0.x;  x[1]=v0.y;  x[2]=v0.z;  x[3]=v0.w;
            x[4]=v1.x;  x[5]=v1.y;  x[6]=v1.z;  x[7]=v1.w;
            x[8]=v2.x;  x[9]=v2.y;  x[10]=v2.z; x[11]=v2.w;
            x[12]=v3.x; x[13]=v3.y; x[14]=v3.z; x[15]=v3.w;
            #pragma unroll
            for (int j = 0; j < 4; ++j) {
                float acc = 0.0f;
                #pragma unroll
                for (int k = 0; k < 11; ++k) {
                    acc = fmaf(GW[k], x[j + k], acc);
                }
                o[s][j] = acc;
            }
        }

        #pragma unroll
        for (int j = 0; j < 4; ++j) {
            const float m1  = o[0][j];
            const float m2  = o[1][j];
            const float e11 = o[2][j];
            const float e22 = o[3][j];
            const float e12 = o[4][j];
            const float m1m2 = m1 * m2;
            const float m1sq = m1 * m1;
            const float m2sq = m2 * m2;
            const float num = (2.0f * m1m2 + C1f) * (2.0f * (e12 - m1m2) + C2f);
            const float den = (m1sq + m2sq + C1f) * ((e11 - m1sq) + (e22 - m2sq) + C2f);
            lsum += num / den;
        }
    }

    // ---------------- Reduction: wave shuffle -> LDS -> one atomic --------
    #pragma unroll
    for (int off = 32; off > 0; off >>= 1) {
        lsum += __shfl_down(lsum, off, 64);
    }
    const int lane = tid & 63;
    const int wv   = tid >> 6;
    if (lane == 0) wsum[wv] = lsum;
    __syncthreads();
    if (tid == 0) {
        const float bs = wsum[0] + wsum[1] + wsum[2] + wsum[3];
        atomicAdd(out, bs);
    }
}

extern "C" void kernel_launch(void* const* d_in, const int* in_sizes, int n_in,
                              void* d_out, int out_size, void* d_ws, size_t ws_size,
                              hipStream_t stream) {
    const float* pred = (const float*)d_in[0];
    const float* targ = (const float*)d_in[1];
    float* out = (float*)d_out;

    hipLaunchKernelGGL(ssim_zero, dim3(1), dim3(1), 0, stream, out);
    hipLaunchKernelGGL(ssim_main, dim3(NBC * HTILES * WTILES), dim3(256), 0, stream,
                       pred, targ, out);
    hipLaunchKernelGGL(ssim_fin, dim3(1), dim3(1), 0, stream, out);
}

// Round 2
// 187.715 us; speedup vs baseline: 1.0539x; 1.0539x over previous
//
#include <hip/hip_runtime.h>

// SSIM loss, fused separable Gaussian (11x11, sigma=1.5) over [32,3,512,512] f32.
// R2: TH 8->4 (LDS 44->21.5 KB, occupancy 3->7 blocks/CU LDS-wise),
//     block-uniform interior/border specialization (no per-element bounds checks,
//     batched 28 global loads for MLP), v_rcp_f32 epilogue, 64-bin atomics in d_ws.

#define IH 512
#define IW 512
#define TH 4                // output rows per tile
#define TW 256              // output cols per tile
#define PW 266              // TW + 10 padded cols
#define RRN 14              // TH + 10 raw rows
#define LST 268             // LDS row stride in floats (1072 B, 16B-aligned)
#define HTILES 128          // 512 / TH
#define WTILES 2
#define NBLK (96 * HTILES * WTILES)   // 24576
#define NBINS 64
#define NPIX 25165824.0f    // 96*512*512

constexpr float GW[11] = {
    0.00102838f, 0.00759877f, 0.03600078f, 0.10936070f, 0.21300554f,
    0.26601173f,
    0.21300554f, 0.10936070f, 0.03600078f, 0.00759877f, 0.00102838f
};
constexpr float C1f = 0.0001f;  // 0.01^2
constexpr float C2f = 0.0009f;  // 0.03^2

__global__ void ssim_zero(float* ws) { ws[threadIdx.x] = 0.0f; }

__global__ void ssim_fin(const float* __restrict__ ws, float* __restrict__ out) {
    float v = ws[threadIdx.x];
    #pragma unroll
    for (int off = 32; off > 0; off >>= 1) v += __shfl_down(v, off, 64);
    if (threadIdx.x == 0) out[0] = 1.0f - v * (1.0f / NPIX);
}

__global__ __launch_bounds__(256) void ssim_main(
    const float* __restrict__ pred,
    const float* __restrict__ targ,
    float* __restrict__ ws)
{
    __shared__ __align__(16) float vlds[5][TH][LST];
    __shared__ float wsum[4];

    const int tid = threadIdx.x;
    const int bid = blockIdx.x;
    const int wt = bid & (WTILES - 1);
    const int ht = (bid >> 1) & (HTILES - 1);
    const int bc = bid >> 8;
    const int h0 = ht * TH;
    const int w0 = wt * TW;
    const float* __restrict__ P = pred + (size_t)bc * (IH * IW);
    const float* __restrict__ T = targ + (size_t)bc * (IH * IW);
    const int rbase = h0 - 5;
    const bool vint = (rbase >= 0) && (rbase + RRN <= IH);  // block-uniform

    // ---------------- Phase 1: vertical FIR, global -> registers -> LDS ---
    for (int cc = tid; cc < PW; cc += 256) {
        const int w = w0 - 5 + cc;
        const bool wok = ((unsigned)w < (unsigned)IW);
        float pv[RRN], tv[RRN];
        if (wok) {
            if (vint) {
                // interior: checkless, fully batched loads
                const float* __restrict__ Pp = P + rbase * IW + w;
                const float* __restrict__ Tp = T + rbase * IW + w;
                #pragma unroll
                for (int rr = 0; rr < RRN; ++rr) {
                    pv[rr] = Pp[rr * IW];
                    tv[rr] = Tp[rr * IW];
                }
            } else {
                // vertical border: clamped address + mask multiply (branchless)
                #pragma unroll
                for (int rr = 0; rr < RRN; ++rr) {
                    const int h = rbase + rr;
                    const int hc = min(max(h, 0), IH - 1);
                    const float m = ((unsigned)h < (unsigned)IH) ? 1.0f : 0.0f;
                    pv[rr] = P[hc * IW + w] * m;
                    tv[rr] = T[hc * IW + w] * m;
                }
            }
        } else {
            #pragma unroll
            for (int rr = 0; rr < RRN; ++rr) { pv[rr] = 0.0f; tv[rr] = 0.0f; }
        }

        float a[5][TH];
        #pragma unroll
        for (int s = 0; s < 5; ++s)
            #pragma unroll
            for (int ro = 0; ro < TH; ++ro) a[s][ro] = 0.0f;

        #pragma unroll
        for (int rr = 0; rr < RRN; ++rr) {
            const float p = pv[rr], t = tv[rr];
            const float pp = p * p;
            const float tt = t * t;
            const float pt = p * t;
            #pragma unroll
            for (int ro = 0; ro < TH; ++ro) {
                const int k = rr - ro;          // compile-time after unroll
                if (k >= 0 && k < 11) {
                    const float g = GW[k];
                    a[0][ro] = fmaf(g, p,  a[0][ro]);
                    a[1][ro] = fmaf(g, t,  a[1][ro]);
                    a[2][ro] = fmaf(g, pp, a[2][ro]);
                    a[3][ro] = fmaf(g, tt, a[3][ro]);
                    a[4][ro] = fmaf(g, pt, a[4][ro]);
                }
            }
        }
        #pragma unroll
        for (int s = 0; s < 5; ++s)
            #pragma unroll
            for (int ro = 0; ro < TH; ++ro)
                vlds[s][ro][cc] = a[s][ro];
    }
    __syncthreads();

    // ---------------- Phase 2: horizontal conv + SSIM epilogue ------------
    const int r  = tid >> 6;            // 0..3
    const int c0 = (tid & 63) << 2;     // 0..252

    float o[5][4];
    #pragma unroll
    for (int s = 0; s < 5; ++s) {
        const float4* base = reinterpret_cast<const float4*>(&vlds[s][r][c0]);
        const float4 v0 = base[0];
        const float4 v1 = base[1];
        const float4 v2 = base[2];
        const float4 v3 = base[3];
        float x[16];
        x[0]=v0.x;  x[1]=v0.y;  x[2]=v0.z;  x[3]=v0.w;
        x[4]=v1.x;  x[5]=v1.y;  x[6]=v1.z;  x[7]=v1.w;
        x[8]=v2.x;  x[9]=v2.y;  x[10]=v2.z; x[11]=v2.w;
        x[12]=v3.x; x[13]=v3.y; x[14]=v3.z; x[15]=v3.w;
        #pragma unroll
        for (int j = 0; j < 4; ++j) {
            float acc = 0.0f;
            #pragma unroll
            for (int k = 0; k < 11; ++k) {
                acc = fmaf(GW[k], x[j + k], acc);
            }
            o[s][j] = acc;
        }
    }

    float lsum = 0.0f;
    #pragma unroll
    for (int j = 0; j < 4; ++j) {
        const float m1  = o[0][j];
        const float m2  = o[1][j];
        const float e11 = o[2][j];
        const float e22 = o[3][j];
        const float e12 = o[4][j];
        const float m1m2 = m1 * m2;
        const float m1sq = m1 * m1;
        const float m2sq = m2 * m2;
        const float num = (2.0f * m1m2 + C1f) * (2.0f * (e12 - m1m2) + C2f);
        const float den = (m1sq + m2sq + C1f) * ((e11 - m1sq) + (e22 - m2sq) + C2f);
        lsum = fmaf(num, __builtin_amdgcn_rcpf(den), lsum);
    }

    // ---------------- Reduction: wave shuffle -> LDS -> binned atomic -----
    #pragma unroll
    for (int off = 32; off > 0; off >>= 1) {
        lsum += __shfl_down(lsum, off, 64);
    }
    const int lane = tid & 63;
    const int wv   = tid >> 6;
    if (lane == 0) wsum[wv] = lsum;
    __syncthreads();
    if (tid == 0) {
        const float bs = wsum[0] + wsum[1] + wsum[2] + wsum[3];
        atomicAdd(&ws[bid & (NBINS - 1)], bs);
    }
}

extern "C" void kernel_launch(void* const* d_in, const int* in_sizes, int n_in,
                              void* d_out, int out_size, void* d_ws, size_t ws_size,
                              hipStream_t stream) {
    const float* pred = (const float*)d_in[0];
    const float* targ = (const float*)d_in[1];
    float* out = (float*)d_out;
    float* wsf = (float*)d_ws;

    hipLaunchKernelGGL(ssim_zero, dim3(1), dim3(NBINS), 0, stream, wsf);
    hipLaunchKernelGGL(ssim_main, dim3(NBLK), dim3(256), 0, stream, pred, targ, wsf);
    hipLaunchKernelGGL(ssim_fin, dim3(1), dim3(64), 0, stream, wsf, out);
}

// Round 3
// 178.887 us; speedup vs baseline: 1.1059x; 1.0493x over previous
//
#include <hip/hip_runtime.h>

// SSIM loss, fused separable Gaussian (11x11, sigma=1.5) over [32,3,512,512] f32.
// R3: __launch_bounds__(256,4) -> VGPR cap 128 (was 48: compiler serialized the
//     28-load batch and rematerialized to fit 8 waves/SIMD; we only need 4).
//     4 FIR chains instead of 5: epilogue only uses E[p^2]+E[t^2] as a sum, so
//     convolve s=p^2+t^2 as one signal (-20% FMA, -20% LDS -> 8 blocks/CU).

#define IH 512
#define IW 512
#define TH 4                // output rows per tile
#define TW 256              // output cols per tile
#define PW 266              // TW + 10 padded cols
#define RRN 14              // TH + 10 raw rows
#define LST 268             // LDS row stride in floats (1072 B, 16B-aligned)
#define HTILES 128          // 512 / TH
#define WTILES 2
#define NBLK (96 * HTILES * WTILES)   // 24576
#define NBINS 64
#define NPIX 25165824.0f    // 96*512*512

constexpr float GW[11] = {
    0.00102838f, 0.00759877f, 0.03600078f, 0.10936070f, 0.21300554f,
    0.26601173f,
    0.21300554f, 0.10936070f, 0.03600078f, 0.00759877f, 0.00102838f
};
constexpr float C1f = 0.0001f;  // 0.01^2
constexpr float C2f = 0.0009f;  // 0.03^2

__global__ void ssim_zero(float* ws) { ws[threadIdx.x] = 0.0f; }

__global__ void ssim_fin(const float* __restrict__ ws, float* __restrict__ out) {
    float v = ws[threadIdx.x];
    #pragma unroll
    for (int off = 32; off > 0; off >>= 1) v += __shfl_down(v, off, 64);
    if (threadIdx.x == 0) out[0] = 1.0f - v * (1.0f / NPIX);
}

// chains: 0 = E[p], 1 = E[t], 2 = E[p^2 + t^2], 3 = E[p*t]
__global__ __launch_bounds__(256, 4) void ssim_main(
    const float* __restrict__ pred,
    const float* __restrict__ targ,
    float* __restrict__ ws)
{
    __shared__ __align__(16) float vlds[4][TH][LST];
    __shared__ float wsum[4];

    const int tid = threadIdx.x;
    const int bid = blockIdx.x;
    const int wt = bid & (WTILES - 1);
    const int ht = (bid >> 1) & (HTILES - 1);
    const int bc = bid >> 8;
    const int h0 = ht * TH;
    const int w0 = wt * TW;
    const float* __restrict__ P = pred + (size_t)bc * (IH * IW);
    const float* __restrict__ T = targ + (size_t)bc * (IH * IW);
    const int rbase = h0 - 5;
    const bool vint = (rbase >= 0) && (rbase + RRN <= IH);  // block-uniform

    // ---------------- Phase 1: vertical FIR, global -> registers -> LDS ---
    for (int cc = tid; cc < PW; cc += 256) {
        const int w = w0 - 5 + cc;
        const bool wok = ((unsigned)w < (unsigned)IW);
        float pv[RRN], tv[RRN];
        if (wok) {
            if (vint) {
                // interior: checkless, fully batched loads (MLP)
                const float* __restrict__ Pp = P + rbase * IW + w;
                const float* __restrict__ Tp = T + rbase * IW + w;
                #pragma unroll
                for (int rr = 0; rr < RRN; ++rr) pv[rr] = Pp[rr * IW];
                #pragma unroll
                for (int rr = 0; rr < RRN; ++rr) tv[rr] = Tp[rr * IW];
            } else {
                // vertical border: clamped address + mask multiply (branchless)
                #pragma unroll
                for (int rr = 0; rr < RRN; ++rr) {
                    const int h = rbase + rr;
                    const int hc = min(max(h, 0), IH - 1);
                    const float m = ((unsigned)h < (unsigned)IH) ? 1.0f : 0.0f;
                    pv[rr] = P[hc * IW + w] * m;
                    tv[rr] = T[hc * IW + w] * m;
                }
            }
        } else {
            #pragma unroll
            for (int rr = 0; rr < RRN; ++rr) { pv[rr] = 0.0f; tv[rr] = 0.0f; }
        }

        float a[4][TH];
        #pragma unroll
        for (int s = 0; s < 4; ++s)
            #pragma unroll
            for (int ro = 0; ro < TH; ++ro) a[s][ro] = 0.0f;

        #pragma unroll
        for (int rr = 0; rr < RRN; ++rr) {
            const float p = pv[rr], t = tv[rr];
            const float tt = t * t;
            const float s2 = fmaf(p, p, tt);   // p^2 + t^2
            const float pt = p * t;
            #pragma unroll
            for (int ro = 0; ro < TH; ++ro) {
                const int k = rr - ro;          // compile-time after unroll
                if (k >= 0 && k < 11) {
                    const float g = GW[k];
                    a[0][ro] = fmaf(g, p,  a[0][ro]);
                    a[1][ro] = fmaf(g, t,  a[1][ro]);
                    a[2][ro] = fmaf(g, s2, a[2][ro]);
                    a[3][ro] = fmaf(g, pt, a[3][ro]);
                }
            }
        }
        #pragma unroll
        for (int s = 0; s < 4; ++s)
            #pragma unroll
            for (int ro = 0; ro < TH; ++ro)
                vlds[s][ro][cc] = a[s][ro];
    }
    __syncthreads();

    // ---------------- Phase 2: horizontal conv + SSIM epilogue ------------
    const int r  = tid >> 6;            // 0..3
    const int c0 = (tid & 63) << 2;     // 0..252

    float o[4][4];
    #pragma unroll
    for (int s = 0; s < 4; ++s) {
        const float4* base = reinterpret_cast<const float4*>(&vlds[s][r][c0]);
        const float4 v0 = base[0];
        const float4 v1 = base[1];
        const float4 v2 = base[2];
        const float4 v3 = base[3];
        float x[16];
        x[0]=v0.x;  x[1]=v0.y;  x[2]=v0.z;  x[3]=v0.w;
        x[4]=v1.x;  x[5]=v1.y;  x[6]=v1.z;  x[7]=v1.w;
        x[8]=v2.x;  x[9]=v2.y;  x[10]=v2.z; x[11]=v2.w;
        x[12]=v3.x; x[13]=v3.y; x[14]=v3.z; x[15]=v3.w;
        #pragma unroll
        for (int j = 0; j < 4; ++j) {
            float acc = 0.0f;
            #pragma unroll
            for (int k = 0; k < 11; ++k) {
                acc = fmaf(GW[k], x[j + k], acc);
            }
            o[s][j] = acc;
        }
    }

    float lsum = 0.0f;
    #pragma unroll
    for (int j = 0; j < 4; ++j) {
        const float m1  = o[0][j];
        const float m2  = o[1][j];
        const float sPP = o[2][j];      // E[p^2]+E[t^2]
        const float e12 = o[3][j];
        const float m1m2 = m1 * m2;
        const float msq  = fmaf(m1, m1, m2 * m2);   // m1^2 + m2^2
        const float num = fmaf(2.0f, m1m2, C1f) * fmaf(2.0f, (e12 - m1m2), C2f);
        const float den = (msq + C1f) * ((sPP - msq) + C2f);
        lsum = fmaf(num, __builtin_amdgcn_rcpf(den), lsum);
    }

    // ---------------- Reduction: wave shuffle -> LDS -> binned atomic -----
    #pragma unroll
    for (int off = 32; off > 0; off >>= 1) {
        lsum += __shfl_down(lsum, off, 64);
    }
    const int lane = tid & 63;
    const int wv   = tid >> 6;
    if (lane == 0) wsum[wv] = lsum;
    __syncthreads();
    if (tid == 0) {
        const float bs = wsum[0] + wsum[1] + wsum[2] + wsum[3];
        atomicAdd(&ws[bid & (NBINS - 1)], bs);
    }
}

extern "C" void kernel_launch(void* const* d_in, const int* in_sizes, int n_in,
                              void* d_out, int out_size, void* d_ws, size_t ws_size,
                              hipStream_t stream) {
    const float* pred = (const float*)d_in[0];
    const float* targ = (const float*)d_in[1];
    float* out = (float*)d_out;
    float* wsf = (float*)d_ws;

    hipLaunchKernelGGL(ssim_zero, dim3(1), dim3(NBINS), 0, stream, wsf);
    hipLaunchKernelGGL(ssim_main, dim3(NBLK), dim3(256), 0, stream, pred, targ, wsf);
    hipLaunchKernelGGL(ssim_fin, dim3(1), dim3(64), 0, stream, wsf, out);
}

// Round 5
// 175.911 us; speedup vs baseline: 1.1246x; 1.0169x over previous
//
#include <hip/hip_runtime.h>

// SSIM loss, fused separable Gaussian (11x11, sigma=1.5) over [32,3,512,512] f32.
// R5 = R4 with the Phase-2 load bug fixed (needed 14 f32x2 = 7 float4 per stat
// pair, had 4 -> uninitialized taps -> NaN).
// R4: (a) packed f32 math — 4 FIR chains as 2 float2 chains with identical
//     weights: (E[p],E[t]) and (E[p^2+t^2],E[p*t]) -> v_pk_fma_f32;
//     (b) scalar-base addressing (uniform row base, constant lane index);
//     (c) block-uniform border handling, horizontal mask at LDS-store.

typedef float f32x2 __attribute__((ext_vector_type(2)));

#define IH 512
#define IW 512
#define TH 4                // output rows per tile
#define TW 256              // output cols per tile
#define PW 266              // TW + 10 padded cols
#define LPW 268             // LDS row stride in f32x2 (2144 B, 16B-aligned)
#define RRN 14              // TH + 10 raw rows
#define HTILES 128          // 512 / TH
#define WTILES 2
#define NBLK (96 * HTILES * WTILES)   // 24576
#define NBINS 64
#define NPIX 25165824.0f    // 96*512*512

constexpr float GW[11] = {
    0.00102838f, 0.00759877f, 0.03600078f, 0.10936070f, 0.21300554f,
    0.26601173f,
    0.21300554f, 0.10936070f, 0.03600078f, 0.00759877f, 0.00102838f
};
constexpr float C1f = 0.0001f;  // 0.01^2
constexpr float C2f = 0.0009f;  // 0.03^2

__global__ void ssim_zero(float* ws) { ws[threadIdx.x] = 0.0f; }

__global__ void ssim_fin(const float* __restrict__ ws, float* __restrict__ out) {
    float v = ws[threadIdx.x];
    #pragma unroll
    for (int off = 32; off > 0; off >>= 1) v += __shfl_down(v, off, 64);
    if (threadIdx.x == 0) out[0] = 1.0f - v * (1.0f / NPIX);
}

__global__ __launch_bounds__(256, 4) void ssim_main(
    const float* __restrict__ pred,
    const float* __restrict__ targ,
    float* __restrict__ ws)
{
    __shared__ __align__(16) f32x2 lds01[TH][LPW];  // (E[p], E[t])
    __shared__ __align__(16) f32x2 lds23[TH][LPW];  // (E[p^2+t^2], E[p*t])
    __shared__ float wsum[4];

    const int tid = threadIdx.x;
    const int bid = blockIdx.x;
    const int wt = bid & (WTILES - 1);
    const int ht = (bid >> 1) & (HTILES - 1);
    const int bc = bid >> 8;
    const int h0 = ht * TH;
    const int w0 = wt * TW;
    const float* __restrict__ P = pred + (size_t)bc * (IH * IW);
    const float* __restrict__ T = targ + (size_t)bc * (IH * IW);
    const int rbase = h0 - 5;
    const bool vint = (rbase >= 0) && (rbase + RRN <= IH);  // block-uniform

    // ---------------- Phase 1: vertical FIR, global -> registers -> LDS ---
    for (int cc = tid; cc < PW; cc += 256) {
        const int w = w0 - 5 + cc;
        const bool wok = ((unsigned)w < (unsigned)IW);
        const int wc = wok ? w : (w < 0 ? 0 : IW - 1);   // clamped lane index

        f32x2 sig[RRN];
        if (vint) {
            // interior: uniform row bases (SGPR), constant lane index -> no
            // per-load VALU address math; all 28 loads batch-issue.
            const float* __restrict__ rp = P + (size_t)rbase * IW;
            const float* __restrict__ rt = T + (size_t)rbase * IW;
            #pragma unroll
            for (int rr = 0; rr < RRN; ++rr) {
                sig[rr].x = rp[wc];
                sig[rr].y = rt[wc];
                rp += IW; rt += IW;
            }
        } else {
            // border: per-row validity is block-uniform -> scalar branches
            #pragma unroll
            for (int rr = 0; rr < RRN; ++rr) {
                const int h = rbase + rr;
                if ((unsigned)h < (unsigned)IH) {
                    sig[rr].x = P[(size_t)h * IW + wc];
                    sig[rr].y = T[(size_t)h * IW + wc];
                } else {
                    sig[rr].x = 0.0f; sig[rr].y = 0.0f;
                }
            }
        }

        f32x2 a01[TH], a23[TH];
        #pragma unroll
        for (int ro = 0; ro < TH; ++ro) {
            a01[ro].x = 0.f; a01[ro].y = 0.f;
            a23[ro].x = 0.f; a23[ro].y = 0.f;
        }

        #pragma unroll
        for (int rr = 0; rr < RRN; ++rr) {
            const f32x2 s01 = sig[rr];                       // (p, t)
            f32x2 s23;
            s23.x = fmaf(s01.x, s01.x, s01.y * s01.y);       // p^2 + t^2
            s23.y = s01.x * s01.y;                           // p*t
            #pragma unroll
            for (int ro = 0; ro < TH; ++ro) {
                const int k = rr - ro;       // compile-time after unroll
                if (k >= 0 && k < 11) {
                    const f32x2 g = {GW[k], GW[k]};
                    a01[ro] = __builtin_elementwise_fma(g, s01, a01[ro]);
                    a23[ro] = __builtin_elementwise_fma(g, s23, a23[ro]);
                }
            }
        }

        const float wm = wok ? 1.0f : 0.0f;      // horizontal zero-pad mask
        const f32x2 wmv = {wm, wm};
        #pragma unroll
        for (int ro = 0; ro < TH; ++ro) {
            lds01[ro][cc] = a01[ro] * wmv;
            lds23[ro][cc] = a23[ro] * wmv;
        }
    }
    __syncthreads();

    // ---------------- Phase 2: horizontal conv + SSIM epilogue ------------
    const int r  = tid >> 6;            // 0..3
    const int c0 = (tid & 63) << 2;     // 0..252

    // need f32x2 elements c0 .. c0+13  (taps j+k, j<4, k<11) -> 7 float4 loads
    f32x2 x01[14], x23[14];
    {
        const float4* b01 = reinterpret_cast<const float4*>(&lds01[r][c0]);
        const float4* b23 = reinterpret_cast<const float4*>(&lds23[r][c0]);
        #pragma unroll
        for (int q = 0; q < 7; ++q) {
            const float4 u = b01[q];
            x01[2*q+0].x = u.x; x01[2*q+0].y = u.y;
            x01[2*q+1].x = u.z; x01[2*q+1].y = u.w;
            const float4 v = b23[q];
            x23[2*q+0].x = v.x; x23[2*q+0].y = v.y;
            x23[2*q+1].x = v.z; x23[2*q+1].y = v.w;
        }
    }

    float lsum = 0.0f;
    #pragma unroll
    for (int j = 0; j < 4; ++j) {
        f32x2 acc01; acc01.x = 0.f; acc01.y = 0.f;
        f32x2 acc23; acc23.x = 0.f; acc23.y = 0.f;
        #pragma unroll
        for (int k = 0; k < 11; ++k) {
            const f32x2 g = {GW[k], GW[k]};
            acc01 = __builtin_elementwise_fma(g, x01[j + k], acc01);
            acc23 = __builtin_elementwise_fma(g, x23[j + k], acc23);
        }
        const float m1  = acc01.x;
        const float m2  = acc01.y;
        const float sPP = acc23.x;      // E[p^2]+E[t^2]
        const float e12 = acc23.y;      // E[p*t]
        const float m1m2 = m1 * m2;
        const float msq  = fmaf(m1, m1, m2 * m2);   // m1^2 + m2^2
        const float num = fmaf(2.0f, m1m2, C1f) * fmaf(2.0f, (e12 - m1m2), C2f);
        const float den = (msq + C1f) * ((sPP - msq) + C2f);
        lsum = fmaf(num, __builtin_amdgcn_rcpf(den), lsum);
    }

    // ---------------- Reduction: wave shuffle -> LDS -> binned atomic -----
    #pragma unroll
    for (int off = 32; off > 0; off >>= 1) {
        lsum += __shfl_down(lsum, off, 64);
    }
    const int lane = tid & 63;
    const int wv   = tid >> 6;
    if (lane == 0) wsum[wv] = lsum;
    __syncthreads();
    if (tid == 0) {
        const float bs = wsum[0] + wsum[1] + wsum[2] + wsum[3];
        atomicAdd(&ws[bid & (NBINS - 1)], bs);
    }
}

extern "C" void kernel_launch(void* const* d_in, const int* in_sizes, int n_in,
                              void* d_out, int out_size, void* d_ws, size_t ws_size,
                              hipStream_t stream) {
    const float* pred = (const float*)d_in[0];
    const float* targ = (const float*)d_in[1];
    float* out = (float*)d_out;
    float* wsf = (float*)d_ws;

    hipLaunchKernelGGL(ssim_zero, dim3(1), dim3(NBINS), 0, stream, wsf);
    hipLaunchKernelGGL(ssim_main, dim3(NBLK), dim3(256), 0, stream, pred, targ, wsf);
    hipLaunchKernelGGL(ssim_fin, dim3(1), dim3(64), 0, stream, wsf, out);
}